// Round 6
// baseline (276.160 us; speedup 1.0000x reference)
//
#include <hip/hip_runtime.h>
#include <cmath>

// ---------------------------------------------------------------------------
// JPEG compress (YCbCr + 2x2 chroma pool + 8x8 DCT + quantize/round).
//
// Numerics contract (VERIFIED r4, absmax 0.0): f32 end-to-end, every
// accumulation step is mul-then-add with TWO roundings (numpy baseline-SIMD,
// no FMA). r5 lesson: __f*_rn builtins are PLAIN ops in HIP headers -- the
// backend may contract mul+add into FMA depending on code shape (r5's
// 16-chain loop / pool tail got fused -> absmax 1.0). Therefore ALL
// value-path mul/add/sub are inline-asm v_mul_f32 / v_add_f32 / v_sub_f32:
// the compiler cannot fuse across an asm boundary. fdiv/rint are not
// contractible and stay as builtins (matched in r4).
//
// Recipe per output (DO NOT CHANGE):
//   t_c   = rn(x_c * 255)
//   y     = chain c=R,G,B: a = rn(a + rn(t_c*k_c))
//   cb/cr = same chain, + 128
//   pool  = ((p00+p01)+p10)+p11 then *0.25, then -128
//   y     : -128 after chain
//   dct_i = 64-step chain j=(x,y) row-major from 0: a = rn(a + rn(X_j*T_ij))
//   outv  = rintf( rn( rn(sc_i * dct_i) / q_i ) )
//
// Structure (r5, latency fix kept): 3072 wg x 256 thr (4 waves).
//   Phase 1: cooperative staging of 64 X-blocks into LDS Xs[64][65].
//   Phase 2: thread = (block, i-quarter): 16 outputs, 16 chains, one
//            ds_read per j; DCT rows wave-uniform -> scalar pipe ("s" asm
//            constraint); 4 contiguous float4 stores at the end.
// ---------------------------------------------------------------------------

namespace jc {

constexpr double c1 = 0.98078528040323044912618223613424;  // cos(1*pi/16)
constexpr double c2 = 0.92387953251128675612818318939679;  // cos(2*pi/16)
constexpr double c3 = 0.83146961230254523707878837761791;  // cos(3*pi/16)
constexpr double c4 = 0.70710678118654752440084436210485;  // cos(4*pi/16)
constexpr double c5 = 0.55557023301960222474283081394853;  // cos(5*pi/16)
constexpr double c6 = 0.38268343236508977172845998403040;  // cos(6*pi/16)
constexpr double c7 = 0.19509032201612826784828486847702;  // cos(7*pi/16)
constexpr double alpha0 = 0.70710678118654746171979706919384;  // 1.0/np.sqrt(2)

struct Tab {
  float t[4096];   // t[i*64+j] = f32(CX[x][u]*CX[y][v]), i=(u,v), j=(x,y)
  float sc[64];    // f32(f64(alpha_u*alpha_v)*0.25)
  float yq[64];
  float cq[64];
  constexpr Tab() : t(), sc(), yq(), cq() {
    const double CX[8][8] = {  // CX[x][u] = cos((2x+1)u*pi/16)
      {1.0,  c1,  c2,  c3,  c4,  c5,  c6,  c7},
      {1.0,  c3,  c6, -c7, -c4, -c1, -c2, -c5},
      {1.0,  c5, -c6, -c1, -c4,  c7,  c2,  c3},
      {1.0,  c7, -c2, -c5,  c4,  c3, -c6, -c1},
      {1.0, -c7, -c2,  c5,  c4, -c3, -c6,  c1},
      {1.0, -c5, -c6,  c1, -c4, -c7,  c2, -c3},
      {1.0, -c3,  c6,  c7, -c4,  c1, -c2,  c5},
      {1.0, -c1,  c2, -c3,  c4, -c5,  c6, -c7}};
    for (int i = 0; i < 64; ++i) {
      const int u = i >> 3, v = i & 7;
      for (int j = 0; j < 64; ++j) {
        const int x = j >> 3, y = j & 7;
        t[i * 64 + j] = (float)(CX[x][u] * CX[y][v]);
      }
      const double au = (u == 0) ? alpha0 : 1.0;
      const double av = (v == 0) ? alpha0 : 1.0;
      sc[i] = (float)((au * av) * 0.25);
    }
    const int YT[64] = {
      16, 11, 10, 16, 24, 40, 51, 61,
      12, 12, 14, 19, 26, 58, 60, 55,
      14, 13, 16, 24, 40, 57, 69, 56,
      14, 17, 22, 29, 51, 87, 80, 62,
      18, 22, 37, 56, 68, 109, 103, 77,
      24, 35, 55, 64, 81, 104, 113, 92,
      49, 64, 78, 87, 103, 121, 120, 101,
      72, 92, 95, 98, 112, 100, 103, 99};
    const int CT[64] = {
      17, 18, 24, 47, 99, 99, 99, 99,
      18, 21, 26, 66, 99, 99, 99, 99,
      24, 26, 56, 99, 99, 99, 99, 99,
      47, 66, 99, 99, 99, 99, 99, 99,
      99, 99, 99, 99, 99, 99, 99, 99,
      99, 99, 99, 99, 99, 99, 99, 99,
      99, 99, 99, 99, 99, 99, 99, 99,
      99, 99, 99, 99, 99, 99, 99, 99};
    for (int i = 0; i < 64; ++i) {
      yq[i] = (float)YT[i];
      cq[i] = (float)CT[i];
    }
  }
};

__device__ constexpr Tab TT;

}  // namespace jc

// ---- contraction-proof f32 ops (asm boundary blocks FMA formation) ----
__device__ __forceinline__ float vmul(float a, float b) {
  float r; asm("v_mul_f32 %0, %1, %2" : "=v"(r) : "v"(a), "v"(b)); return r;
}
__device__ __forceinline__ float vadd(float a, float b) {
  float r; asm("v_add_f32 %0, %1, %2" : "=v"(r) : "v"(a), "v"(b)); return r;
}
__device__ __forceinline__ float vsubf(float a, float b) {  // a - b
  float r; asm("v_sub_f32 %0, %1, %2" : "=v"(r) : "v"(a), "v"(b)); return r;
}
// multiply with wave-uniform first operand kept on the scalar pipe
__device__ __forceinline__ float vmul_sv(float su, float v) {
  float r; asm("v_mul_f32 %0, %1, %2" : "=v"(r) : "s"(su), "v"(v)); return r;
}

__device__ __forceinline__ float ylum(float R, float G, float B) {
  const float tR = vmul(R, 255.0f);
  const float tG = vmul(G, 255.0f);
  const float tB = vmul(B, 255.0f);
  float a = vmul(tR, 0.299f);
  a = vadd(a, vmul(tG, 0.587f));
  a = vadd(a, vmul(tB, 0.114f));
  return a;
}

// chroma chain from pre-scaled t values (tR=rn(R*255) etc.), + 128 shift
__device__ __forceinline__ float chro_t(float tR, float tG, float tB,
                                        float kR, float kG, float kB) {
  float a = vmul(tR, kR);
  a = vadd(a, vmul(tG, kG));
  a = vadd(a, vmul(tB, kB));
  return vadd(a, 128.0f);
}

// grid: 3072 workgroups x 256 threads (4 waves).
// wg 0..2047: Y group = 64x64-px region (64 blocks).
// wg 2048..3071: chroma group = 128x64-px region (32 patches -> 32 Cb + 32 Cr).
__global__ __launch_bounds__(256, 4) void jpeg_kernel(const float* __restrict__ img,
                                                      float* __restrict__ out) {
  __shared__ float Xs[64][65];  // 64 blocks x 64 X-values, +1 pad

  const int wid = blockIdx.x;
  const int t = threadIdx.x;
  const int sub = t & 63;   // phase-2: block index within group
  const int iq = t >> 6;    // phase-2: i-quarter (wave-uniform)

  float* outp;
  const float* qt;

  if (wid < 2048) {
    // ================= Y group =================
    const int b = wid >> 6;
    const int r = wid & 63;
    const int gby = (r >> 3) * 8 + (sub >> 3);
    const int gbx = (r & 7) * 8 + (sub & 7);
    // --- phase 1: stage rows 2*iq, 2*iq+1 of block `sub` ---
    const float* rp = img + (size_t)b * 786432 + gby * 4096 + gbx * 8;
#pragma unroll
    for (int xr = 0; xr < 2; ++xr) {
      const int x = iq * 2 + xr;
      const float4 r0 = *(const float4*)(rp + x * 512);
      const float4 r1 = *(const float4*)(rp + x * 512 + 4);
      const float4 g0 = *(const float4*)(rp + 262144 + x * 512);
      const float4 g1 = *(const float4*)(rp + 262144 + x * 512 + 4);
      const float4 b0 = *(const float4*)(rp + 524288 + x * 512);
      const float4 b1 = *(const float4*)(rp + 524288 + x * 512 + 4);
      float* xp = &Xs[sub][x * 8];
      xp[0] = vsubf(ylum(r0.x, g0.x, b0.x), 128.0f);
      xp[1] = vsubf(ylum(r0.y, g0.y, b0.y), 128.0f);
      xp[2] = vsubf(ylum(r0.z, g0.z, b0.z), 128.0f);
      xp[3] = vsubf(ylum(r0.w, g0.w, b0.w), 128.0f);
      xp[4] = vsubf(ylum(r1.x, g1.x, b1.x), 128.0f);
      xp[5] = vsubf(ylum(r1.y, g1.y, b1.y), 128.0f);
      xp[6] = vsubf(ylum(r1.z, g1.z, b1.z), 128.0f);
      xp[7] = vsubf(ylum(r1.w, g1.w, b1.w), 128.0f);
    }
    outp = out + ((size_t)(b * 4096 + gby * 64 + gbx) << 6);
    qt = jc::TT.yq;
  } else {
    // ================= chroma group =================
    const int cw = wid - 2048;
    const int b = cw >> 5;
    const int reg = cw & 31;  // 8 rows x 4 cols of 128x64-px regions
    // --- phase 1: thread stages chroma row `rr` of patch `p` (Cb AND Cr) ---
    {
      const int p = t & 31;
      const int rr = t >> 5;  // 0..7
      const int cby = (reg >> 2) * 4 + (p >> 3);
      const int cbx = (reg & 3) * 8 + (p & 7);
      const float* base = img + (size_t)b * 786432 + cby * 8192 + cbx * 16 + rr * 1024;
      float px[3][2][16];
#pragma unroll
      for (int c = 0; c < 3; ++c) {
#pragma unroll
        for (int rw = 0; rw < 2; ++rw) {
          const float* p0 = base + c * 262144 + rw * 512;
#pragma unroll
          for (int q = 0; q < 4; ++q) {
            const float4 v = *(const float4*)(p0 + q * 4);
            px[c][rw][q * 4 + 0] = v.x;
            px[c][rw][q * 4 + 1] = v.y;
            px[c][rw][q * 4 + 2] = v.z;
            px[c][rw][q * 4 + 3] = v.w;
          }
        }
      }
#pragma unroll
      for (int pc = 0; pc < 8; ++pc) {
#pragma unroll
        for (int typ = 0; typ < 2; ++typ) {
          const float kR = typ ? 0.5f       : -0.168736f;
          const float kG = typ ? -0.418688f : -0.331264f;
          const float kB = typ ? -0.081312f : 0.5f;
          float pv[4];
#pragma unroll
          for (int q = 0; q < 4; ++q) {        // (row rw, col c0/c1) in order
            const int rw = q >> 1;
            const int cc = 2 * pc + (q & 1);
            const float tR = vmul(px[0][rw][cc], 255.0f);
            const float tG = vmul(px[1][rw][cc], 255.0f);
            const float tB = vmul(px[2][rw][cc], 255.0f);
            pv[q] = chro_t(tR, tG, tB, kR, kG, kB);
          }
          const float ssum = vadd(vadd(vadd(pv[0], pv[1]), pv[2]), pv[3]);
          const float m = vmul(ssum, 0.25f);
          Xs[typ * 32 + p][rr * 8 + pc] = vsubf(m, 128.0f);
        }
      }
    }
    // --- phase-2 output location for block `sub` ---
    const int typ = sub >> 5;
    const int pp = sub & 31;
    const int cby = (reg >> 2) * 4 + (pp >> 3);
    const int cbx = (reg & 3) * 8 + (pp & 7);
    outp = out + 8388608 + (size_t)typ * 2097152 +
           ((size_t)(b * 1024 + cby * 32 + cbx) << 6);
    qt = jc::TT.cq;
  }

  __syncthreads();

  // ========== phase 2: DCT + quantize, 16 outputs per thread ==========
  const int ibase = __builtin_amdgcn_readfirstlane(iq) * 16;  // wave-uniform
  const float* __restrict__ xrow = Xs[sub];
  const float* tr = jc::TT.t + ibase * 64;

  float acc[16];
#pragma unroll
  for (int k = 0; k < 16; ++k) acc[k] = 0.0f;

#pragma unroll
  for (int j = 0; j < 64; ++j) {
    const float xv = xrow[j];  // one ds_read, reused by 16 chains
#pragma unroll
    for (int k = 0; k < 16; ++k) {
      // a = rn(a + rn(T_ij * X_j)); T uniform -> scalar-pipe operand
      acc[k] = vadd(acc[k], vmul_sv(tr[k * 64 + j], xv));
    }
  }

  float* op = outp + ibase;
#pragma unroll
  for (int k4 = 0; k4 < 4; ++k4) {
    float4 stv;
    stv.x = rintf(__fdiv_rn(vmul_sv(jc::TT.sc[ibase + k4 * 4 + 0], acc[k4 * 4 + 0]),
                            qt[ibase + k4 * 4 + 0]));
    stv.y = rintf(__fdiv_rn(vmul_sv(jc::TT.sc[ibase + k4 * 4 + 1], acc[k4 * 4 + 1]),
                            qt[ibase + k4 * 4 + 1]));
    stv.z = rintf(__fdiv_rn(vmul_sv(jc::TT.sc[ibase + k4 * 4 + 2], acc[k4 * 4 + 2]),
                            qt[ibase + k4 * 4 + 2]));
    stv.w = rintf(__fdiv_rn(vmul_sv(jc::TT.sc[ibase + k4 * 4 + 3], acc[k4 * 4 + 3]),
                            qt[ibase + k4 * 4 + 3]));
    *(float4*)(op + k4 * 4) = stv;
  }
}

extern "C" void kernel_launch(void* const* d_in, const int* in_sizes, int n_in,
                              void* d_out, int out_size, void* d_ws, size_t ws_size,
                              hipStream_t stream) {
  (void)in_sizes; (void)n_in; (void)d_ws; (void)ws_size; (void)out_size;
  const float* img = (const float*)d_in[0];
  float* out = (float*)d_out;
  jpeg_kernel<<<dim3(3072), dim3(256), 0, stream>>>(img, out);
}

// Round 7
// 183.812 us; speedup vs baseline: 1.5024x; 1.5024x over previous
//
#include <hip/hip_runtime.h>
#include <cmath>

// ---------------------------------------------------------------------------
// JPEG compress (YCbCr + 2x2 chroma pool + 8x8 DCT + quantize/round).
//
// Numerics contract (VERIFIED r4/r6, absmax 0.0): f32 end-to-end, every
// accumulation step is mul-then-add with TWO roundings (numpy baseline-SIMD,
// no FMA). __f*_rn builtins are contractible in HIP -- all value-path
// mul/add/sub are inline-asm v_mul_f32 / v_add_f32 / v_sub_f32 (asm boundary
// blocks FMA formation). fdiv/rint stay as builtins (verified r4/r6).
//
// Recipe per output (DO NOT CHANGE):
//   t_c   = rn(x_c * 255)
//   y     = chain c=R,G,B: a = rn(a + rn(t_c*k_c));  X = rn(a - 128)
//   cb/cr = same chain + 128; pool ((p00+p01)+p10)+p11 * 0.25; - 128
//   dct_i = 64-step chain j=(x,y) row-major from 0: a = rn(a + rn(T_ij*X_j))
//   outv  = rintf( rn( rn(sc_i * dct_i) / q_i ) )
//
// R6->R7 structure (fixes: double image read; scalar-load-serialized DCT):
//   2048 wg x 256 thr; wg = one 64x64-px region -> 64 Y + 16 Cb + 16 Cr
//   blocks staged in LDS from ONE pixel read (t values shared Y/chroma).
//   Phase 2: lane = output i; DCT row T[i][*] in 64 VGPRs (loaded once per
//   wave from a TRANSPOSED constexpr table, coalesced); X[j] wave-uniform ->
//   ds_read_b128 broadcast. Inner loop = pure VOP2 v_mul/v_add. 2-block
//   interleave for add-chain ILP. Coalesced 256B stores per block.
// ---------------------------------------------------------------------------

namespace jc {

constexpr double c1 = 0.98078528040323044912618223613424;  // cos(1*pi/16)
constexpr double c2 = 0.92387953251128675612818318939679;  // cos(2*pi/16)
constexpr double c3 = 0.83146961230254523707878837761791;  // cos(3*pi/16)
constexpr double c4 = 0.70710678118654752440084436210485;  // cos(4*pi/16)
constexpr double c5 = 0.55557023301960222474283081394853;  // cos(5*pi/16)
constexpr double c6 = 0.38268343236508977172845998403040;  // cos(6*pi/16)
constexpr double c7 = 0.19509032201612826784828486847702;  // cos(7*pi/16)
constexpr double alpha0 = 0.70710678118654746171979706919384;  // 1.0/np.sqrt(2)

struct Tab {
  float tt[4096];  // TRANSPOSED: tt[j*64+i] = f32(CX[x][u]*CX[y][v]), j=(x,y), i=(u,v)
  float sc[64];    // f32(f64(alpha_u*alpha_v)*0.25)
  float yq[64];
  float cq[64];
  constexpr Tab() : tt(), sc(), yq(), cq() {
    const double CX[8][8] = {  // CX[x][u] = cos((2x+1)u*pi/16)
      {1.0,  c1,  c2,  c3,  c4,  c5,  c6,  c7},
      {1.0,  c3,  c6, -c7, -c4, -c1, -c2, -c5},
      {1.0,  c5, -c6, -c1, -c4,  c7,  c2,  c3},
      {1.0,  c7, -c2, -c5,  c4,  c3, -c6, -c1},
      {1.0, -c7, -c2,  c5,  c4, -c3, -c6,  c1},
      {1.0, -c5, -c6,  c1, -c4, -c7,  c2, -c3},
      {1.0, -c3,  c6,  c7, -c4,  c1, -c2,  c5},
      {1.0, -c1,  c2, -c3,  c4, -c5,  c6, -c7}};
    for (int i = 0; i < 64; ++i) {
      const int u = i >> 3, v = i & 7;
      for (int j = 0; j < 64; ++j) {
        const int x = j >> 3, y = j & 7;
        tt[j * 64 + i] = (float)(CX[x][u] * CX[y][v]);
      }
      const double au = (u == 0) ? alpha0 : 1.0;
      const double av = (v == 0) ? alpha0 : 1.0;
      sc[i] = (float)((au * av) * 0.25);
    }
    const int YT[64] = {
      16, 11, 10, 16, 24, 40, 51, 61,
      12, 12, 14, 19, 26, 58, 60, 55,
      14, 13, 16, 24, 40, 57, 69, 56,
      14, 17, 22, 29, 51, 87, 80, 62,
      18, 22, 37, 56, 68, 109, 103, 77,
      24, 35, 55, 64, 81, 104, 113, 92,
      49, 64, 78, 87, 103, 121, 120, 101,
      72, 92, 95, 98, 112, 100, 103, 99};
    const int CT[64] = {
      17, 18, 24, 47, 99, 99, 99, 99,
      18, 21, 26, 66, 99, 99, 99, 99,
      24, 26, 56, 99, 99, 99, 99, 99,
      47, 66, 99, 99, 99, 99, 99, 99,
      99, 99, 99, 99, 99, 99, 99, 99,
      99, 99, 99, 99, 99, 99, 99, 99,
      99, 99, 99, 99, 99, 99, 99, 99,
      99, 99, 99, 99, 99, 99, 99, 99};
    for (int i = 0; i < 64; ++i) {
      yq[i] = (float)YT[i];
      cq[i] = (float)CT[i];
    }
  }
};

__device__ constexpr Tab TT;

}  // namespace jc

// ---- contraction-proof f32 ops (asm boundary blocks FMA formation) ----
__device__ __forceinline__ float vmul(float a, float b) {
  float r; asm("v_mul_f32 %0, %1, %2" : "=v"(r) : "v"(a), "v"(b)); return r;
}
__device__ __forceinline__ float vadd(float a, float b) {
  float r; asm("v_add_f32 %0, %1, %2" : "=v"(r) : "v"(a), "v"(b)); return r;
}
__device__ __forceinline__ float vsubf(float a, float b) {  // a - b
  float r; asm("v_sub_f32 %0, %1, %2" : "=v"(r) : "v"(a), "v"(b)); return r;
}

// chroma chain from pre-scaled t values (tR=rn(R*255) etc.), + 128 shift
__device__ __forceinline__ float chro_t(float tR, float tG, float tB,
                                        float kR, float kG, float kB) {
  float a = vmul(tR, kR);
  a = vadd(a, vmul(tG, kG));
  a = vadd(a, vmul(tB, kB));
  return vadd(a, 128.0f);
}

// grid: 2048 workgroups x 256 threads (4 waves). wg = 64x64-px region of one
// batch image: 64 Y blocks + 16 Cb + 16 Cr blocks, all from one pixel read.
__global__ __launch_bounds__(256, 4) void jpeg_kernel(const float* __restrict__ img,
                                                      float* __restrict__ out) {
  __shared__ float Xs[96][68];  // rows: 0..63 Y, 64..79 Cb, 80..95 Cr; stride 272B (16B-aligned)

  const int wid = blockIdx.x;
  const int t = threadIdx.x;
  const int b = wid >> 6;   // batch 0..31
  const int r = wid & 63;   // region 0..63 (8x8 grid of 64x64-px regions)

  // ================= phase 1: merged staging =================
  {
    const int yb = t & 63;   // Y block 0..63 within region
    const int q = t >> 6;    // row-pair 0..3 within the Y block
    const int by = yb >> 3, bx = yb & 7;
    const int prow = (r >> 3) * 64 + by * 8 + 2 * q;  // global pixel row (top of pair)
    const int pcol = (r & 7) * 64 + bx * 8;
    const float* rp = img + (size_t)b * 786432 + (size_t)prow * 512 + pcol;

    float tv[3][2][8];  // rn(px*255): channel, row-in-pair, col
#pragma unroll
    for (int c = 0; c < 3; ++c) {
#pragma unroll
      for (int rr = 0; rr < 2; ++rr) {
        const float* p0 = rp + c * 262144 + rr * 512;
        const float4 va = *(const float4*)(p0);
        const float4 vb = *(const float4*)(p0 + 4);
        tv[c][rr][0] = vmul(va.x, 255.0f);
        tv[c][rr][1] = vmul(va.y, 255.0f);
        tv[c][rr][2] = vmul(va.z, 255.0f);
        tv[c][rr][3] = vmul(va.w, 255.0f);
        tv[c][rr][4] = vmul(vb.x, 255.0f);
        tv[c][rr][5] = vmul(vb.y, 255.0f);
        tv[c][rr][6] = vmul(vb.z, 255.0f);
        tv[c][rr][7] = vmul(vb.w, 255.0f);
      }
    }
    // --- Y: 16 values -> Xs[yb][16q .. 16q+15] (j = (2q+rr)*8 + y) ---
#pragma unroll
    for (int rr = 0; rr < 2; ++rr) {
#pragma unroll
      for (int y = 0; y < 8; ++y) {
        float a = vmul(tv[0][rr][y], 0.299f);
        a = vadd(a, vmul(tv[1][rr][y], 0.587f));
        a = vadd(a, vmul(tv[2][rr][y], 0.114f));
        Xs[yb][16 * q + rr * 8 + y] = vsubf(a, 128.0f);
      }
    }
    // --- chroma: this thread owns chroma row lcr, cols 4bx..4bx+3 ---
    const int lcr = 4 * by + q;  // 0..31 within region
#pragma unroll
    for (int pc = 0; pc < 4; ++pc) {
      const int lcc = 4 * bx + pc;
      const int crow = 64 + ((lcr >> 3) * 4 + (lcc >> 3));  // Cb block row in Xs
      const int cell = (lcr & 7) * 8 + (lcc & 7);
      const int e = 2 * pc, o = 2 * pc + 1;
      // Cb
      {
        const float p00 = chro_t(tv[0][0][e], tv[1][0][e], tv[2][0][e], -0.168736f, -0.331264f, 0.5f);
        const float p01 = chro_t(tv[0][0][o], tv[1][0][o], tv[2][0][o], -0.168736f, -0.331264f, 0.5f);
        const float p10 = chro_t(tv[0][1][e], tv[1][1][e], tv[2][1][e], -0.168736f, -0.331264f, 0.5f);
        const float p11 = chro_t(tv[0][1][o], tv[1][1][o], tv[2][1][o], -0.168736f, -0.331264f, 0.5f);
        const float s = vadd(vadd(vadd(p00, p01), p10), p11);
        Xs[crow][cell] = vsubf(vmul(s, 0.25f), 128.0f);
      }
      // Cr
      {
        const float p00 = chro_t(tv[0][0][e], tv[1][0][e], tv[2][0][e], 0.5f, -0.418688f, -0.081312f);
        const float p01 = chro_t(tv[0][0][o], tv[1][0][o], tv[2][0][o], 0.5f, -0.418688f, -0.081312f);
        const float p10 = chro_t(tv[0][1][e], tv[1][1][e], tv[2][1][e], 0.5f, -0.418688f, -0.081312f);
        const float p11 = chro_t(tv[0][1][o], tv[1][1][o], tv[2][1][o], 0.5f, -0.418688f, -0.081312f);
        const float s = vadd(vadd(vadd(p00, p01), p10), p11);
        Xs[crow + 16][cell] = vsubf(vmul(s, 0.25f), 128.0f);
      }
    }
  }

  // --- per-lane DCT row into VGPRs (global loads overlap staging/barrier) ---
  const int w = t >> 6;     // wave 0..3
  const int lane = t & 63;  // output index i
  float T[64];
#pragma unroll
  for (int j = 0; j < 64; ++j) T[j] = jc::TT.tt[j * 64 + lane];
  const float scv = jc::TT.sc[lane];
  const float yqv = jc::TT.yq[lane];
  const float cqv = jc::TT.cq[lane];

  __syncthreads();

  // ================= phase 2: DCT + quantize =================
  // wave w handles blocks w*24 .. w*24+23 (2-block interleave for ILP)
  const int ybase = b * 4096 + (r >> 3) * 512 + (r & 7) * 8;  // + by*64 + bx
  const int cbase = b * 1024 + (r >> 3) * 128 + (r & 7) * 4;  // + cy*32 + cx

  auto emit = [&](int blk, float acc) {
    float qv;
    size_t off;
    if (blk < 64) {
      qv = yqv;
      off = ((size_t)(ybase + (blk >> 3) * 64 + (blk & 7))) << 6;
    } else {
      qv = cqv;
      const int cc = blk & 15;
      off = (size_t)8388608 + (blk >= 80 ? (size_t)2097152 : (size_t)0) +
            (((size_t)(cbase + (cc >> 2) * 32 + (cc & 3))) << 6);
    }
    out[off + lane] = rintf(__fdiv_rn(vmul(scv, acc), qv));
  };

  for (int n = 0; n < 24; n += 2) {
    const int bA = w * 24 + n;
    const int bB = bA + 1;
    float a0 = 0.0f, a1 = 0.0f;
#pragma unroll
    for (int j4 = 0; j4 < 16; ++j4) {
      const float4 xA = *(const float4*)&Xs[bA][j4 * 4];  // broadcast (uniform addr)
      const float4 xB = *(const float4*)&Xs[bB][j4 * 4];
      a0 = vadd(a0, vmul(T[4 * j4 + 0], xA.x));
      a1 = vadd(a1, vmul(T[4 * j4 + 0], xB.x));
      a0 = vadd(a0, vmul(T[4 * j4 + 1], xA.y));
      a1 = vadd(a1, vmul(T[4 * j4 + 1], xB.y));
      a0 = vadd(a0, vmul(T[4 * j4 + 2], xA.z));
      a1 = vadd(a1, vmul(T[4 * j4 + 2], xB.z));
      a0 = vadd(a0, vmul(T[4 * j4 + 3], xA.w));
      a1 = vadd(a1, vmul(T[4 * j4 + 3], xB.w));
    }
    emit(bA, a0);
    emit(bB, a1);
  }
}

extern "C" void kernel_launch(void* const* d_in, const int* in_sizes, int n_in,
                              void* d_out, int out_size, void* d_ws, size_t ws_size,
                              hipStream_t stream) {
  (void)in_sizes; (void)n_in; (void)d_ws; (void)ws_size; (void)out_size;
  const float* img = (const float*)d_in[0];
  float* out = (float*)d_out;
  jpeg_kernel<<<dim3(2048), dim3(256), 0, stream>>>(img, out);
}